// Round 13
// baseline (159.421 us; speedup 1.0000x reference)
//
#include <hip/hip_runtime.h>
#include <hip/hip_fp16.h>
#include <math.h>

// Problem constants
#define BB   64
#define CC   8
#define HH   256
#define WW   256
#define EMB  64
#define LAT  32
#define HW   (HH*WW)            // 65536
#define PLANE 65536
#define IMG  (CC*HW)            // 524288 floats per batch image

// Output layout (flat concat, fp32):
#define OFF_XDEC  0
#define OFF_EMB   33554432
#define OFF_SCALE 33556480
#define OFF_SHEAR 33556864
#define OFF_ROT   33557248
#define OFF_TRANS 33557632
#define OFF_MASK  33558016

// ws layout (float offsets):
#define WS_SUMS   0
#define WS_THETA  512
#define WS_MASK   2048
#define WS_ACC    2112
#define WS_BUF0   4096                      // fp16 [B][HW][8] = 16.77M floats
#define WS_BUF1   (4096 + 16777216)

// warpA tile geometry: output 16x64, LDS tile 20x68 (margin 2), 512-thread blocks
#define TH 16
#define TW 64
#define SR 20                               // TH+4
#define SC 68                               // TW+4
#define SN (SR*SC)                          // 1360 px, 21.76 KB as uint4

typedef float v2f __attribute__((ext_vector_type(2)));

// ---------------- K0: zero the atomic sum buffer ----------------
__global__ void k_zero(float* __restrict__ ws) {
    ws[WS_SUMS + threadIdx.x] = 0.f;        // 512 threads
}

__device__ __forceinline__ unsigned pack2(float a, float b) {
    __half2 t = __floats2half2_rn(a, b);
    return *(unsigned*)&t;
}
__device__ __forceinline__ float2 up2(unsigned v) {
    __half2 h = *(__half2*)&v;
    return __half22float2(h);
}

// ---------------- K1: fused GAP-sum + planar fp32 -> channel-last fp16 transpose ----------------
__global__ void k_meanT(const float* __restrict__ x, uint4* __restrict__ outp,
                        float* __restrict__ sums) {
    int bid = blockIdx.x;
    int b = bid >> 6;
    int hq = bid & 63;
    int r = threadIdx.x >> 6;      // 0..3
    int lane = threadIdx.x & 63;
    int h = hq * 4 + r;
    const float* ib = x + (size_t)b * IMG + h * WW + 4 * lane;
    float4 v0 = *(const float4*)(ib + 0 * PLANE);
    float4 v1 = *(const float4*)(ib + 1 * PLANE);
    float4 v2 = *(const float4*)(ib + 2 * PLANE);
    float4 v3 = *(const float4*)(ib + 3 * PLANE);
    float4 v4 = *(const float4*)(ib + 4 * PLANE);
    float4 v5 = *(const float4*)(ib + 5 * PLANE);
    float4 v6 = *(const float4*)(ib + 6 * PLANE);
    float4 v7 = *(const float4*)(ib + 7 * PLANE);

    uint4* ob = outp + (size_t)b * HW + h * WW + 4 * lane;
#define PIXOUT(J, COMP) { uint4 u; \
    u.x = pack2(v0.COMP, v1.COMP); u.y = pack2(v2.COMP, v3.COMP); \
    u.z = pack2(v4.COMP, v5.COMP); u.w = pack2(v6.COMP, v7.COMP); ob[J] = u; }
    PIXOUT(0, x) PIXOUT(1, y) PIXOUT(2, z) PIXOUT(3, w)
#undef PIXOUT

    float p[CC];
    p[0] = (v0.x + v0.y) + (v0.z + v0.w);
    p[1] = (v1.x + v1.y) + (v1.z + v1.w);
    p[2] = (v2.x + v2.y) + (v2.z + v2.w);
    p[3] = (v3.x + v3.y) + (v3.z + v3.w);
    p[4] = (v4.x + v4.y) + (v4.z + v4.w);
    p[5] = (v5.x + v5.y) + (v5.z + v5.w);
    p[6] = (v6.x + v6.y) + (v6.z + v6.w);
    p[7] = (v7.x + v7.y) + (v7.z + v7.w);

    __shared__ float part[4][CC];
    #pragma unroll
    for (int ch = 0; ch < CC; ch++) {
        float v = p[ch];
        for (int off = 32; off > 0; off >>= 1) v += __shfl_down(v, off, 64);
        if (lane == 0) part[r][ch] = v;
    }
    __syncthreads();
    if (threadIdx.x < CC) {
        float v = (part[0][threadIdx.x] + part[1][threadIdx.x]) +
                  (part[2][threadIdx.x] + part[3][threadIdx.x]);
        atomicAdd(&sums[b * CC + threadIdx.x], v);
    }
}

// ---------------- K2: thetas + mask; zero xt accumulators ----------------
__global__ void k_params(const float* __restrict__ sums,
                         const float* __restrict__ W_ae, const float* __restrict__ W_rot,
                         const float* __restrict__ W_scale, const float* __restrict__ W_shear,
                         const float* __restrict__ W_trans, const float* __restrict__ W_mask,
                         float* __restrict__ ws, float* __restrict__ out) {
    int b = blockIdx.x;
    int t = threadIdx.x;                       // 0..63

    if (t < CC) ws[WS_ACC + b * CC + t] = 0.f;

    __shared__ float emb_s[EMB];
    {
        float s = 0.f;
        #pragma unroll
        for (int c = 0; c < CC; c++)
            s += (sums[b * CC + c] * (1.0f / (float)HW)) * W_ae[c * EMB + t];
        emb_s[t] = s;
    }
    __syncthreads();

    if (t < 24) {
        int h = t / 6, k = t % 6;
        const float* Wt = (h == 0) ? W_rot : (h == 1) ? W_scale : (h == 2) ? W_shear : W_trans;
        float s = 0.f;
        #pragma unroll
        for (int e = 0; e < EMB; e++) s += emb_s[e] * Wt[e * 6 + k];
        const float eyev = (k == 0 || k == 4) ? 1.0f : 0.0f;
        float th = s * 0.1f + eyev;
        ws[WS_THETA + h * (BB * 6) + b * 6 + k] = th;
        int off = (h == 0) ? OFF_ROT : (h == 1) ? OFF_SCALE : (h == 2) ? OFF_SHEAR : OFF_TRANS;
        out[off + b * 6 + k] = th;
    } else if (t == 24) {
        float s = 0.f;
        #pragma unroll
        for (int e = 0; e < EMB; e++) s += emb_s[e] * W_mask[e];
        float mk = 1.0f / (1.0f + expf(-s));
        ws[WS_MASK + b] = mk;
        out[OFF_MASK + b] = mk;
    }
}

// ---------------- shared helpers ----------------
struct Corners {
    int x0c, x1c, y0c, y1c;
    float w00, w01, w10, w11;
};

__device__ __forceinline__ Corners affine_corners(float t00, float t01, float t02,
                                                  float t10, float t11, float t12,
                                                  int gh, int gw) {
    float X = ((float)gw + 0.5f) * (2.0f / (float)WW) - 1.0f;
    float Y = ((float)gh + 0.5f) * (2.0f / (float)HH) - 1.0f;
    float gx = X * t00 + Y * t01 + t02;
    float gy = X * t10 + Y * t11 + t12;
    float ix = ((gx + 1.0f) * (float)WW - 1.0f) * 0.5f;
    float iy = ((gy + 1.0f) * (float)HH - 1.0f) * 0.5f;
    float x0f = floorf(ix), y0f = floorf(iy);
    int x0 = (int)x0f, y0 = (int)y0f, x1 = x0 + 1, y1 = y0 + 1;
    float wx1 = ix - x0f, wy1 = iy - y0f, wx0 = 1.f - wx1, wy0 = 1.f - wy1;
    float fx0 = ((unsigned)x0 < (unsigned)WW) ? 1.f : 0.f;
    float fx1 = ((unsigned)x1 < (unsigned)WW) ? 1.f : 0.f;
    float fy0 = ((unsigned)y0 < (unsigned)HH) ? 1.f : 0.f;
    float fy1 = ((unsigned)y1 < (unsigned)HH) ? 1.f : 0.f;
    Corners c;
    c.x0c = min(max(x0, 0), WW - 1); c.x1c = min(max(x1, 0), WW - 1);
    c.y0c = min(max(y0, 0), HH - 1); c.y1c = min(max(y1, 0), HH - 1);
    c.w00 = wy0*wx0*fy0*fx0; c.w01 = wy0*wx1*fy0*fx1;
    c.w10 = wy1*wx0*fy1*fx0; c.w11 = wy1*wx1*fy1*fx1;
    return c;
}

// packed-fp16 8-channel bilinear blend
__device__ __forceinline__ uint4 bilerp8_pk(uint4 a00, uint4 a01, uint4 a10, uint4 a11,
                                            __half2 h00, __half2 h01, __half2 h10, __half2 h11) {
    uint4 u;
#define BLEND(COMP) { \
    __half2 r = __hmul2(*(__half2*)&a00.COMP, h00); \
    r = __hfma2(*(__half2*)&a01.COMP, h01, r); \
    r = __hfma2(*(__half2*)&a10.COMP, h10, r); \
    r = __hfma2(*(__half2*)&a11.COMP, h11, r); \
    u.COMP = *(unsigned*)&r; }
    BLEND(x) BLEND(y) BLEND(z) BLEND(w)
#undef BLEND
    return u;
}

// swizzled LDS index: XOR sc bits [2:0] with bits [5:3] (bijective involution per row).
__device__ __forceinline__ int lidx(int sr, int sc) {
    sr = min(max(sr, 0), SR - 1);
    sc = min(max(sc, 0), SC - 1);
    return sr * SC + (sc ^ ((sc >> 3) & 7));
}

// Stage 1: gather from GLOBAL channel-last fp16, write warped tile into swizzled LDS.
template<int NT>
__device__ __forceinline__ void stage_g2l(uint4* __restrict__ buf,
                                          const uint4* __restrict__ pb,
                                          const float* __restrict__ th,
                                          int oh, int ow, int tid) {
    float t00 = th[0], t01 = th[1], t02 = th[2], t10 = th[3], t11 = th[4], t12 = th[5];
    for (int i = tid; i < SN; i += NT) {
        int lr = i / SC, lc = i - lr * SC;
        Corners c = affine_corners(t00, t01, t02, t10, t11, t12, oh - 2 + lr, ow - 2 + lc);
        uint4 a00 = pb[c.y0c * WW + c.x0c], a01 = pb[c.y0c * WW + c.x1c];
        uint4 a10 = pb[c.y1c * WW + c.x0c], a11 = pb[c.y1c * WW + c.x1c];
        __half2 h00 = __float2half2_rn(c.w00), h01 = __float2half2_rn(c.w01);
        __half2 h10 = __float2half2_rn(c.w10), h11 = __float2half2_rn(c.w11);
        buf[lr * SC + (lc ^ ((lc >> 3) & 7))] =
            bilerp8_pk(a00, a01, a10, a11, h00, h01, h10, h11);
    }
}

// ---------------- K3: warps 1+2 (rotation, scale): hb0 -> hb1 ----------------
__global__ __launch_bounds__(512) void k_warpA(const uint4* __restrict__ in,
                                               uint4* __restrict__ out,
                                               const float* __restrict__ ws) {
    __shared__ uint4 buf[SN];
    int bid = (int)gridDim.x - 1 - (int)blockIdx.x;
    int b = bid >> 6;                    // 64 tiles per batch: 16 row-tiles x 4 col-tiles
    int tile = bid & 63;
    int oh = (tile >> 2) * TH;
    int ow = (tile & 3) * TW;
    int tid = threadIdx.x;
    const uint4* pb = in + (size_t)b * HW;

    stage_g2l<512>(buf, pb, ws + WS_THETA + 0 * (BB * 6) + b * 6, oh, ow, tid);  // rotation
    __syncthreads();

    const float* th = ws + WS_THETA + 1 * (BB * 6) + b * 6;                  // scale
    float t00 = th[0], t01 = th[1], t02 = th[2], t10 = th[3], t11 = th[4], t12 = th[5];
    uint4* ob = out + (size_t)b * HW;
    #pragma unroll
    for (int j = 0; j < 2; ++j) {
        int i = tid + j * 512;
        int lr = i >> 6, lc = i & 63;
        int gh = oh + lr, gw = ow + lc;
        Corners c = affine_corners(t00, t01, t02, t10, t11, t12, gh, gw);
        uint4 a00 = buf[lidx(c.y0c - oh + 2, c.x0c - ow + 2)];
        uint4 a01 = buf[lidx(c.y0c - oh + 2, c.x1c - ow + 2)];
        uint4 a10 = buf[lidx(c.y1c - oh + 2, c.x0c - ow + 2)];
        uint4 a11 = buf[lidx(c.y1c - oh + 2, c.x1c - ow + 2)];
        __half2 h00 = __float2half2_rn(c.w00), h01 = __float2half2_rn(c.w01);
        __half2 h10 = __float2half2_rn(c.w10), h11 = __float2half2_rn(c.w11);
        ob[gh * WW + gw] = bilerp8_pk(a00, a01, a10, a11, h00, h01, h10, h11);
    }
}

// ---------------- K4: warps 3+4 (shear+translation composed? NO — direct gather) ----------------
// Barrier-free: 512 threads, 4 px/thread, block = 8 full rows x 256 cols.
// Stage "shear" output is consumed immediately? No — this kernel does BOTH remaining
// warps? It cannot (they are sequential resamples). It does ONLY translation; shear
// stays in warpA? No: warpA does rotation+scale. So warpB must do shear (gather from
// hb1) THEN translation. We keep the LDS tile ONLY for the shear intermediate, but
// the translation stage gathers from that tile; stores are full-row float4.
// Layout: block covers 8 rows x 256 cols = 2048 px; LDS tile = 12 x 260 (margin 2).
#define W_R 12
#define W_C 260
__global__ __launch_bounds__(512) void k_warpB(const uint4* __restrict__ in,
                                               const float* __restrict__ ws,
                                               const float* __restrict__ W_dec,
                                               float* __restrict__ out,
                                               float* __restrict__ acc) {
    __shared__ uint4 buf[W_R * W_C];    // 48.75 KB
    __shared__ v2f Wd2[CC][4];
    __shared__ float part[8][CC];
    int bid = blockIdx.x;
    int b = bid >> 5;                   // 32 row-octets per batch
    int rq = bid & 31;
    int oh = rq * 8;
    int tid = threadIdx.x;
    if (tid < CC * 4) {
        int ch = tid >> 2, j = tid & 3;
        v2f w; w.x = W_dec[ch * CC + 2 * j]; w.y = W_dec[ch * CC + 2 * j + 1];
        Wd2[ch][j] = w;
    }
    const uint4* pb = in + (size_t)b * HW;

    // shear stage: gather global -> LDS tile rows [oh-2, oh+10) x cols [-2, 258)
    {
        const float* th = ws + WS_THETA + 2 * (BB * 6) + b * 6;
        float t00 = th[0], t01 = th[1], t02 = th[2], t10 = th[3], t11 = th[4], t12 = th[5];
        for (int i = tid; i < W_R * W_C; i += 512) {
            int lr = i / W_C, lc = i - lr * W_C;
            Corners c = affine_corners(t00, t01, t02, t10, t11, t12, oh - 2 + lr, lc - 2);
            uint4 a00 = pb[c.y0c * WW + c.x0c], a01 = pb[c.y0c * WW + c.x1c];
            uint4 a10 = pb[c.y1c * WW + c.x0c], a11 = pb[c.y1c * WW + c.x1c];
            __half2 h00 = __float2half2_rn(c.w00), h01 = __float2half2_rn(c.w01);
            __half2 h10 = __float2half2_rn(c.w10), h11 = __float2half2_rn(c.w11);
            buf[lr * W_C + (lc ^ ((lc >> 3) & 7))] =
                bilerp8_pk(a00, a01, a10, a11, h00, h01, h10, h11);
        }
    }
    __syncthreads();

    float mk = ws[WS_MASK + b];
    const float* th = ws + WS_THETA + 3 * (BB * 6) + b * 6;    // translation
    float t00 = th[0], t01 = th[1], t02 = th[2], t10 = th[3], t11 = th[4], t12 = th[5];

    int wv = tid >> 6, lane = tid & 63;
    int gh = oh + wv;                   // one full row per wave
    int col0 = 4 * lane;                // 4 consecutive px per thread

    float sl[CC];
    #pragma unroll
    for (int ch = 0; ch < CC; ch++) sl[ch] = 0.f;
    float od[CC][4];

    #pragma unroll
    for (int px = 0; px < 4; px++) {
        int gw = col0 + px;
        Corners c = affine_corners(t00, t01, t02, t10, t11, t12, gh, gw);
        int sr0 = min(max(c.y0c - oh + 2, 0), W_R - 1);
        int sr1 = min(max(c.y1c - oh + 2, 0), W_R - 1);
        int sc0 = min(max(c.x0c + 2, 0), W_C - 1);
        int sc1 = min(max(c.x1c + 2, 0), W_C - 1);
        uint4 a00 = buf[sr0 * W_C + (sc0 ^ ((sc0 >> 3) & 7))];
        uint4 a01 = buf[sr0 * W_C + (sc1 ^ ((sc1 >> 3) & 7))];
        uint4 a10 = buf[sr1 * W_C + (sc0 ^ ((sc0 >> 3) & 7))];
        uint4 a11 = buf[sr1 * W_C + (sc1 ^ ((sc1 >> 3) & 7))];
        __half2 h00 = __float2half2_rn(c.w00 * mk), h01 = __float2half2_rn(c.w01 * mk);
        __half2 h10 = __float2half2_rn(c.w10 * mk), h11 = __float2half2_rn(c.w11 * mk);
        uint4 u = bilerp8_pk(a00, a01, a10, a11, h00, h01, h10, h11);

        float2 s01 = up2(u.x), s23 = up2(u.y), s45 = up2(u.z), s67 = up2(u.w);
        float s[CC] = {s01.x, s01.y, s23.x, s23.y, s45.x, s45.y, s67.x, s67.y};

        #pragma unroll
        for (int ch = 0; ch < CC; ch++) sl[ch] += s[ch];

        v2f o2[4];
        #pragma unroll
        for (int j = 0; j < 4; j++) { o2[j].x = 0.f; o2[j].y = 0.f; }
        #pragma unroll
        for (int ch = 0; ch < CC; ch++) {
            v2f sb; sb.x = s[ch]; sb.y = s[ch];
            #pragma unroll
            for (int j = 0; j < 4; j++)
                o2[j] = __builtin_elementwise_fma(sb, Wd2[ch][j], o2[j]);
        }
        #pragma unroll
        for (int j = 0; j < 4; j++) { od[2*j][px] = o2[j].x; od[2*j+1][px] = o2[j].y; }
    }

    // full-row float4 stores: each wave writes one contiguous 1 KB row per plane
    size_t base = (size_t)b * IMG + (size_t)gh * WW + col0;
    #pragma unroll
    for (int d = 0; d < CC; d++) {
        float4 f4 = make_float4(od[d][0], od[d][1], od[d][2], od[d][3]);
        *(float4*)(out + OFF_XDEC + base + d * PLANE) = f4;
    }

    #pragma unroll
    for (int ch = 0; ch < CC; ch++) {
        float v = sl[ch];
        for (int off = 32; off > 0; off >>= 1) v += __shfl_down(v, off, 64);
        if (lane == 0) part[wv][ch] = v;
    }
    __syncthreads();
    if (tid < CC) {
        float v = 0.f;
        #pragma unroll
        for (int w = 0; w < 8; w++) v += part[w][tid];
        atomicAdd(&acc[b * CC + tid], v);
    }
}

// ---------------- K5: emb = (acc/HW) @ W_enc ----------------
__global__ void k_emb(const float* __restrict__ acc, const float* __restrict__ W_enc,
                      float* __restrict__ out) {
    for (int i = threadIdx.x; i < BB * LAT; i += 256) {
        int b = i >> 5, l = i & 31;
        float s = 0.f;
        #pragma unroll
        for (int c = 0; c < CC; c++)
            s += (acc[b * CC + c] * (1.0f / (float)HW)) * W_enc[c * LAT + l];
        out[OFF_EMB + i] = s;
    }
}

extern "C" void kernel_launch(void* const* d_in, const int* in_sizes, int n_in,
                              void* d_out, int out_size, void* d_ws, size_t ws_size,
                              hipStream_t stream) {
    const float* x       = (const float*)d_in[0];
    const float* W_ae    = (const float*)d_in[1];
    const float* W_rot   = (const float*)d_in[2];
    const float* W_scale = (const float*)d_in[3];
    const float* W_shear = (const float*)d_in[4];
    const float* W_trans = (const float*)d_in[5];
    const float* W_mask  = (const float*)d_in[6];
    const float* W_enc   = (const float*)d_in[7];
    const float* W_dec   = (const float*)d_in[8];

    float* ws   = (float*)d_ws;
    float* out  = (float*)d_out;
    float* sums = ws + WS_SUMS;
    float* acc  = ws + WS_ACC;
    uint4* hb0  = (uint4*)(ws + WS_BUF0);
    uint4* hb1  = (uint4*)(ws + WS_BUF1);

    k_zero<<<1, 512, 0, stream>>>(ws);
    k_meanT<<<BB * (HH / 4), 256, 0, stream>>>(x, hb0, sums);
    k_params<<<BB, 64, 0, stream>>>(sums, W_ae, W_rot, W_scale, W_shear, W_trans, W_mask, ws, out);
    k_warpA<<<BB * 64, 512, 0, stream>>>(hb0, hb1, ws);                 // rotation + scale
    k_warpB<<<BB * 32, 512, 0, stream>>>(hb1, ws, W_dec, out, acc);     // shear + translation + epilogue
    k_emb<<<1, 256, 0, stream>>>(acc, W_enc, out);
}

// Round 14
// 134.456 us; speedup vs baseline: 1.1857x; 1.1857x over previous
//
#include <hip/hip_runtime.h>
#include <hip/hip_fp16.h>
#include <math.h>

// Problem constants
#define BB   64
#define CC   8
#define HH   256
#define WW   256
#define EMB  64
#define LAT  32
#define HW   (HH*WW)            // 65536
#define PLANE 65536
#define IMG  (CC*HW)            // 524288 floats per batch image

// Output layout (flat concat, fp32):
#define OFF_XDEC  0
#define OFF_EMB   33554432
#define OFF_SCALE 33556480
#define OFF_SHEAR 33556864
#define OFF_ROT   33557248
#define OFF_TRANS 33557632
#define OFF_MASK  33558016

// ws layout (float offsets):
#define WS_THETA  512
#define WS_MASK   2048
#define WS_ACC    2112
#define WS_BUF0   4096                      // fp16 [B][HW][8] = 16.77M floats
#define WS_BUF1   (4096 + 16777216)
// per-(b,hq) GAP partials (64*64*8 floats) live at the head of the hb1 region:
// written by k_meanT, consumed by k_params, then overwritten by k_warpA's output.

// tile geometry: output 16x64, LDS tile 20x68 (margin 2), 512-thread blocks, 2 px/thread
#define TH 16
#define TW 64
#define SR 20                               // TH+4
#define SC 68                               // TW+4
#define SN (SR*SC)                          // 1360 px, 21.76 KB as uint4

typedef float v2f __attribute__((ext_vector_type(2)));

__device__ __forceinline__ unsigned pack2(float a, float b) {
    __half2 t = __floats2half2_rn(a, b);
    return *(unsigned*)&t;
}
__device__ __forceinline__ float2 up2(unsigned v) {
    __half2 h = *(__half2*)&v;
    return __half22float2(h);
}

// ---------------- K1: fused GAP-partials + planar fp32 -> channel-last fp16 transpose ----------------
// Non-atomic: block (b,hq) writes its 8 channel partial sums to partials[(b*64+hq)*8+c].
__global__ void k_meanT(const float* __restrict__ x, uint4* __restrict__ outp,
                        float* __restrict__ partials) {
    int bid = blockIdx.x;
    int b = bid >> 6;
    int hq = bid & 63;
    int r = threadIdx.x >> 6;      // 0..3
    int lane = threadIdx.x & 63;
    int h = hq * 4 + r;
    const float* ib = x + (size_t)b * IMG + h * WW + 4 * lane;
    float4 v0 = *(const float4*)(ib + 0 * PLANE);
    float4 v1 = *(const float4*)(ib + 1 * PLANE);
    float4 v2 = *(const float4*)(ib + 2 * PLANE);
    float4 v3 = *(const float4*)(ib + 3 * PLANE);
    float4 v4 = *(const float4*)(ib + 4 * PLANE);
    float4 v5 = *(const float4*)(ib + 5 * PLANE);
    float4 v6 = *(const float4*)(ib + 6 * PLANE);
    float4 v7 = *(const float4*)(ib + 7 * PLANE);

    uint4* ob = outp + (size_t)b * HW + h * WW + 4 * lane;
#define PIXOUT(J, COMP) { uint4 u; \
    u.x = pack2(v0.COMP, v1.COMP); u.y = pack2(v2.COMP, v3.COMP); \
    u.z = pack2(v4.COMP, v5.COMP); u.w = pack2(v6.COMP, v7.COMP); ob[J] = u; }
    PIXOUT(0, x) PIXOUT(1, y) PIXOUT(2, z) PIXOUT(3, w)
#undef PIXOUT

    float p[CC];
    p[0] = (v0.x + v0.y) + (v0.z + v0.w);
    p[1] = (v1.x + v1.y) + (v1.z + v1.w);
    p[2] = (v2.x + v2.y) + (v2.z + v2.w);
    p[3] = (v3.x + v3.y) + (v3.z + v3.w);
    p[4] = (v4.x + v4.y) + (v4.z + v4.w);
    p[5] = (v5.x + v5.y) + (v5.z + v5.w);
    p[6] = (v6.x + v6.y) + (v6.z + v6.w);
    p[7] = (v7.x + v7.y) + (v7.z + v7.w);

    __shared__ float part[4][CC];
    #pragma unroll
    for (int ch = 0; ch < CC; ch++) {
        float v = p[ch];
        for (int off = 32; off > 0; off >>= 1) v += __shfl_down(v, off, 64);
        if (lane == 0) part[r][ch] = v;
    }
    __syncthreads();
    if (threadIdx.x < CC) {
        float v = (part[0][threadIdx.x] + part[1][threadIdx.x]) +
                  (part[2][threadIdx.x] + part[3][threadIdx.x]);
        partials[bid * CC + threadIdx.x] = v;
    }
}

// ---------------- K2: reduce partials -> thetas + mask; zero xt accumulators ----------------
__global__ void k_params(const float* __restrict__ partials,
                         const float* __restrict__ W_ae, const float* __restrict__ W_rot,
                         const float* __restrict__ W_scale, const float* __restrict__ W_shear,
                         const float* __restrict__ W_trans, const float* __restrict__ W_mask,
                         float* __restrict__ ws, float* __restrict__ out) {
    int b = blockIdx.x;
    int t = threadIdx.x;                       // 0..63

    if (t < CC) ws[WS_ACC + b * CC + t] = 0.f;

    __shared__ float mean_s[CC];
    if (t < CC) {
        float s = 0.f;
        for (int hq = 0; hq < 64; hq++) s += partials[(b * 64 + hq) * CC + t];
        mean_s[t] = s * (1.0f / (float)HW);
    }
    __syncthreads();

    __shared__ float emb_s[EMB];
    {
        float s = 0.f;
        #pragma unroll
        for (int c = 0; c < CC; c++)
            s += mean_s[c] * W_ae[c * EMB + t];
        emb_s[t] = s;
    }
    __syncthreads();

    if (t < 24) {
        int h = t / 6, k = t % 6;
        const float* Wt = (h == 0) ? W_rot : (h == 1) ? W_scale : (h == 2) ? W_shear : W_trans;
        float s = 0.f;
        #pragma unroll
        for (int e = 0; e < EMB; e++) s += emb_s[e] * Wt[e * 6 + k];
        const float eyev = (k == 0 || k == 4) ? 1.0f : 0.0f;
        float th = s * 0.1f + eyev;
        ws[WS_THETA + h * (BB * 6) + b * 6 + k] = th;
        int off = (h == 0) ? OFF_ROT : (h == 1) ? OFF_SCALE : (h == 2) ? OFF_SHEAR : OFF_TRANS;
        out[off + b * 6 + k] = th;
    } else if (t == 24) {
        float s = 0.f;
        #pragma unroll
        for (int e = 0; e < EMB; e++) s += emb_s[e] * W_mask[e];
        float mk = 1.0f / (1.0f + expf(-s));
        ws[WS_MASK + b] = mk;
        out[OFF_MASK + b] = mk;
    }
}

// ---------------- shared helpers ----------------
struct Corners {
    int x0c, x1c, y0c, y1c;
    float w00, w01, w10, w11;
};

__device__ __forceinline__ Corners affine_corners(float t00, float t01, float t02,
                                                  float t10, float t11, float t12,
                                                  int gh, int gw) {
    float X = ((float)gw + 0.5f) * (2.0f / (float)WW) - 1.0f;
    float Y = ((float)gh + 0.5f) * (2.0f / (float)HH) - 1.0f;
    float gx = X * t00 + Y * t01 + t02;
    float gy = X * t10 + Y * t11 + t12;
    float ix = ((gx + 1.0f) * (float)WW - 1.0f) * 0.5f;
    float iy = ((gy + 1.0f) * (float)HH - 1.0f) * 0.5f;
    float x0f = floorf(ix), y0f = floorf(iy);
    int x0 = (int)x0f, y0 = (int)y0f, x1 = x0 + 1, y1 = y0 + 1;
    float wx1 = ix - x0f, wy1 = iy - y0f, wx0 = 1.f - wx1, wy0 = 1.f - wy1;
    float fx0 = ((unsigned)x0 < (unsigned)WW) ? 1.f : 0.f;
    float fx1 = ((unsigned)x1 < (unsigned)WW) ? 1.f : 0.f;
    float fy0 = ((unsigned)y0 < (unsigned)HH) ? 1.f : 0.f;
    float fy1 = ((unsigned)y1 < (unsigned)HH) ? 1.f : 0.f;
    Corners c;
    c.x0c = min(max(x0, 0), WW - 1); c.x1c = min(max(x1, 0), WW - 1);
    c.y0c = min(max(y0, 0), HH - 1); c.y1c = min(max(y1, 0), HH - 1);
    c.w00 = wy0*wx0*fy0*fx0; c.w01 = wy0*wx1*fy0*fx1;
    c.w10 = wy1*wx0*fy1*fx0; c.w11 = wy1*wx1*fy1*fx1;
    return c;
}

// packed-fp16 8-channel bilinear blend
__device__ __forceinline__ uint4 bilerp8_pk(uint4 a00, uint4 a01, uint4 a10, uint4 a11,
                                            __half2 h00, __half2 h01, __half2 h10, __half2 h11) {
    uint4 u;
#define BLEND(COMP) { \
    __half2 r = __hmul2(*(__half2*)&a00.COMP, h00); \
    r = __hfma2(*(__half2*)&a01.COMP, h01, r); \
    r = __hfma2(*(__half2*)&a10.COMP, h10, r); \
    r = __hfma2(*(__half2*)&a11.COMP, h11, r); \
    u.COMP = *(unsigned*)&r; }
    BLEND(x) BLEND(y) BLEND(z) BLEND(w)
#undef BLEND
    return u;
}

// swizzled LDS index: XOR sc bits [2:0] with bits [5:3] (bijective involution per row).
__device__ __forceinline__ int lidx(int sr, int sc) {
    sr = min(max(sr, 0), SR - 1);
    sc = min(max(sc, 0), SC - 1);
    return sr * SC + (sc ^ ((sc >> 3) & 7));
}

// Stage 1: gather from GLOBAL channel-last fp16, write warped tile into swizzled LDS.
template<int NT>
__device__ __forceinline__ void stage_g2l(uint4* __restrict__ buf,
                                          const uint4* __restrict__ pb,
                                          const float* __restrict__ th,
                                          int oh, int ow, int tid) {
    float t00 = th[0], t01 = th[1], t02 = th[2], t10 = th[3], t11 = th[4], t12 = th[5];
    for (int i = tid; i < SN; i += NT) {
        int lr = i / SC, lc = i - lr * SC;
        Corners c = affine_corners(t00, t01, t02, t10, t11, t12, oh - 2 + lr, ow - 2 + lc);
        uint4 a00 = pb[c.y0c * WW + c.x0c], a01 = pb[c.y0c * WW + c.x1c];
        uint4 a10 = pb[c.y1c * WW + c.x0c], a11 = pb[c.y1c * WW + c.x1c];
        __half2 h00 = __float2half2_rn(c.w00), h01 = __float2half2_rn(c.w01);
        __half2 h10 = __float2half2_rn(c.w10), h11 = __float2half2_rn(c.w11);
        buf[lr * SC + (lc ^ ((lc >> 3) & 7))] =
            bilerp8_pk(a00, a01, a10, a11, h00, h01, h10, h11);
    }
}

// ---------------- K3: warps 1+2 (rotation, scale): hb0 -> hb1 ----------------
// Reversed tile order (LIFO reuse of meanT's hb0 writes); VGPR capped for 8 waves/SIMD.
__global__ __launch_bounds__(512, 8) void k_warpA(const uint4* __restrict__ in,
                                                  uint4* __restrict__ out,
                                                  const float* __restrict__ ws) {
    __shared__ uint4 buf[SN];
    int bid = (int)gridDim.x - 1 - (int)blockIdx.x;
    int b = bid >> 6;                    // 64 tiles per batch: 16 row-tiles x 4 col-tiles
    int tile = bid & 63;
    int oh = (tile >> 2) * TH;
    int ow = (tile & 3) * TW;
    int tid = threadIdx.x;
    const uint4* pb = in + (size_t)b * HW;

    stage_g2l<512>(buf, pb, ws + WS_THETA + 0 * (BB * 6) + b * 6, oh, ow, tid);  // rotation
    __syncthreads();

    const float* th = ws + WS_THETA + 1 * (BB * 6) + b * 6;                  // scale
    float t00 = th[0], t01 = th[1], t02 = th[2], t10 = th[3], t11 = th[4], t12 = th[5];
    uint4* ob = out + (size_t)b * HW;
    #pragma unroll
    for (int j = 0; j < 2; ++j) {
        int i = tid + j * 512;
        int lr = i >> 6, lc = i & 63;
        int gh = oh + lr, gw = ow + lc;
        Corners c = affine_corners(t00, t01, t02, t10, t11, t12, gh, gw);
        uint4 a00 = buf[lidx(c.y0c - oh + 2, c.x0c - ow + 2)];
        uint4 a01 = buf[lidx(c.y0c - oh + 2, c.x1c - ow + 2)];
        uint4 a10 = buf[lidx(c.y1c - oh + 2, c.x0c - ow + 2)];
        uint4 a11 = buf[lidx(c.y1c - oh + 2, c.x1c - ow + 2)];
        __half2 h00 = __float2half2_rn(c.w00), h01 = __float2half2_rn(c.w01);
        __half2 h10 = __float2half2_rn(c.w10), h11 = __float2half2_rn(c.w11);
        ob[gh * WW + gw] = bilerp8_pk(a00, a01, a10, a11, h00, h01, h10, h11);
    }
}

// ---------------- K4: warps 3+4 (shear, translation) + mask + decoder + GAP ----------------
// 512 threads, 2 px/thread; VGPR capped for 8 waves/SIMD.
__global__ __launch_bounds__(512, 8) void k_warpB(const uint4* __restrict__ in,
                                                  const float* __restrict__ ws,
                                                  const float* __restrict__ W_dec,
                                                  float* __restrict__ out,
                                                  float* __restrict__ acc) {
    __shared__ uint4 buf[SN];
    __shared__ v2f Wd2[CC][4];          // Wd2[ch][j] = {W_dec[ch][2j], W_dec[ch][2j+1]}
    __shared__ float part[8][CC];
    int bid = blockIdx.x;
    int b = bid >> 6;
    int tile = bid & 63;
    int oh = (tile >> 2) * TH;
    int ow = (tile & 3) * TW;
    int tid = threadIdx.x;
    if (tid < CC * 4) {
        int ch = tid >> 2, j = tid & 3;
        v2f w; w.x = W_dec[ch * CC + 2 * j]; w.y = W_dec[ch * CC + 2 * j + 1];
        Wd2[ch][j] = w;
    }
    const uint4* pb = in + (size_t)b * HW;

    stage_g2l<512>(buf, pb, ws + WS_THETA + 2 * (BB * 6) + b * 6, oh, ow, tid);  // shear
    __syncthreads();

    float mk = ws[WS_MASK + b];
    const float* th = ws + WS_THETA + 3 * (BB * 6) + b * 6;                  // translation
    float t00 = th[0], t01 = th[1], t02 = th[2], t10 = th[3], t11 = th[4], t12 = th[5];

    int wv = tid >> 6, lane = tid & 63;          // wv 0..7
    int r = wv * 2 + (lane >> 5);                // 0..15
    int c0 = (lane & 31) * 2;                    // 0..62
    float sl[CC];
    #pragma unroll
    for (int ch = 0; ch < CC; ch++) sl[ch] = 0.f;
    float od[CC][2];

    #pragma unroll
    for (int px = 0; px < 2; px++) {
        int gh = oh + r, gw = ow + c0 + px;
        Corners c = affine_corners(t00, t01, t02, t10, t11, t12, gh, gw);
        uint4 a00 = buf[lidx(c.y0c - oh + 2, c.x0c - ow + 2)];
        uint4 a01 = buf[lidx(c.y0c - oh + 2, c.x1c - ow + 2)];
        uint4 a10 = buf[lidx(c.y1c - oh + 2, c.x0c - ow + 2)];
        uint4 a11 = buf[lidx(c.y1c - oh + 2, c.x1c - ow + 2)];
        // fold mask into weights: s[ch] comes out pre-masked
        __half2 h00 = __float2half2_rn(c.w00 * mk), h01 = __float2half2_rn(c.w01 * mk);
        __half2 h10 = __float2half2_rn(c.w10 * mk), h11 = __float2half2_rn(c.w11 * mk);
        uint4 u = bilerp8_pk(a00, a01, a10, a11, h00, h01, h10, h11);

        float2 s01 = up2(u.x), s23 = up2(u.y), s45 = up2(u.z), s67 = up2(u.w);
        float s[CC] = {s01.x, s01.y, s23.x, s23.y, s45.x, s45.y, s67.x, s67.y};

        #pragma unroll
        for (int ch = 0; ch < CC; ch++) sl[ch] += s[ch];

        // packed-fp32 decoder: 4 v2f accumulators (d-pairs), v_pk_fma_f32
        v2f o2[4];
        #pragma unroll
        for (int j = 0; j < 4; j++) { o2[j].x = 0.f; o2[j].y = 0.f; }
        #pragma unroll
        for (int ch = 0; ch < CC; ch++) {
            v2f sb; sb.x = s[ch]; sb.y = s[ch];
            #pragma unroll
            for (int j = 0; j < 4; j++)
                o2[j] = __builtin_elementwise_fma(sb, Wd2[ch][j], o2[j]);
        }
        #pragma unroll
        for (int j = 0; j < 4; j++) { od[2*j][px] = o2[j].x; od[2*j+1][px] = o2[j].y; }
    }

    size_t base = (size_t)b * IMG + (size_t)(oh + r) * WW + (ow + c0);
    #pragma unroll
    for (int d = 0; d < CC; d++) {
        float2 f2 = make_float2(od[d][0], od[d][1]);
        *(float2*)(out + OFF_XDEC + base + d * PLANE) = f2;
    }

    #pragma unroll
    for (int ch = 0; ch < CC; ch++) {
        float v = sl[ch];
        for (int off = 32; off > 0; off >>= 1) v += __shfl_down(v, off, 64);
        if (lane == 0) part[wv][ch] = v;
    }
    __syncthreads();
    if (tid < CC) {
        float v = 0.f;
        #pragma unroll
        for (int w = 0; w < 8; w++) v += part[w][tid];
        atomicAdd(&acc[b * CC + tid], v);
    }
}

// ---------------- K5: emb = (acc/HW) @ W_enc ----------------
__global__ void k_emb(const float* __restrict__ acc, const float* __restrict__ W_enc,
                      float* __restrict__ out) {
    for (int i = threadIdx.x; i < BB * LAT; i += 256) {
        int b = i >> 5, l = i & 31;
        float s = 0.f;
        #pragma unroll
        for (int c = 0; c < CC; c++)
            s += (acc[b * CC + c] * (1.0f / (float)HW)) * W_enc[c * LAT + l];
        out[OFF_EMB + i] = s;
    }
}

extern "C" void kernel_launch(void* const* d_in, const int* in_sizes, int n_in,
                              void* d_out, int out_size, void* d_ws, size_t ws_size,
                              hipStream_t stream) {
    const float* x       = (const float*)d_in[0];
    const float* W_ae    = (const float*)d_in[1];
    const float* W_rot   = (const float*)d_in[2];
    const float* W_scale = (const float*)d_in[3];
    const float* W_shear = (const float*)d_in[4];
    const float* W_trans = (const float*)d_in[5];
    const float* W_mask  = (const float*)d_in[6];
    const float* W_enc   = (const float*)d_in[7];
    const float* W_dec   = (const float*)d_in[8];

    float* ws   = (float*)d_ws;
    float* out  = (float*)d_out;
    float* acc  = ws + WS_ACC;
    uint4* hb0  = (uint4*)(ws + WS_BUF0);
    uint4* hb1  = (uint4*)(ws + WS_BUF1);
    // GAP partials live at the head of the hb1 region (dead until warpA writes it)
    float* partials = (float*)hb1;

    k_meanT<<<BB * (HH / 4), 256, 0, stream>>>(x, hb0, partials);
    k_params<<<BB, 64, 0, stream>>>(partials, W_ae, W_rot, W_scale, W_shear, W_trans, W_mask, ws, out);
    k_warpA<<<BB * 64, 512, 0, stream>>>(hb0, hb1, ws);                 // rotation + scale
    k_warpB<<<BB * 64, 512, 0, stream>>>(hb1, ws, W_dec, out, acc);     // shear + translation + epilogue
    k_emb<<<1, 256, 0, stream>>>(acc, W_enc, out);
}